// Round 1
// baseline (100.733 us; speedup 1.0000x reference)
//
#include <hip/hip_runtime.h>

typedef __attribute__((ext_vector_type(8))) short bf16x8;
typedef __attribute__((ext_vector_type(16))) float f32x16;

#define NPTS 32
#define HID 256
#define FANIN 260
#define NKB 17   // 16 h K-blocks (K=16 each) + 1 x/bias block
#define OUTSTRIDE 8192  // NPTS*HID

__device__ __forceinline__ unsigned short f2bf(float f) {
  unsigned u = __builtin_bit_cast(unsigned, f);
  u += 0x7fffu + ((u >> 16) & 1u);   // round-to-nearest-even
  return (unsigned short)(u >> 16);
}

// Pack W (fp32 [32][256][260]) + b (fp32 [32][256]) into per-lane MFMA
// B-fragments, bf16. Layout: pack[((p*8 + ct)*17 + kb)*64 + lane] = 8 bf16.
// For kb<16: B[k = kb*16 + (lane>>5)*8 + i][n = ct*32 + (lane&31)] = W[p][n][k]
// For kb==16 (x/bias): k=0..3 -> W[p][n][256+k], k=4 -> b[p][n], rest 0.
__global__ __launch_bounds__(256) void prep_kernel(
    const float* __restrict__ W, const float* __restrict__ bias,
    bf16x8* __restrict__ pack) {
  int tid = blockIdx.x * 256 + threadIdx.x;
  int lane = tid & 63;
  int kb = (tid >> 6) % NKB;
  int rest = (tid >> 6) / NKB;
  int ct = rest & 7;
  int p = rest >> 3;
  if (p >= NPTS) return;
  int n = ct * 32 + (lane & 31);
  int g = lane >> 5;
  const float* wrow = W + (size_t)(p * HID + n) * FANIN;
  unsigned short e[8];
  if (kb < 16) {
    int k0 = kb * 16 + g * 8;
#pragma unroll
    for (int i = 0; i < 8; ++i) e[i] = f2bf(wrow[k0 + i]);
  } else {
#pragma unroll
    for (int i = 0; i < 8; ++i) e[i] = 0;
    if (g == 0) {
      e[0] = f2bf(wrow[256]);
      e[1] = f2bf(wrow[257]);
      e[2] = f2bf(wrow[258]);
      e[3] = f2bf(wrow[259]);
      e[4] = f2bf(bias[p * HID + n]);
    }
  }
  bf16x8 v;
#pragma unroll
  for (int i = 0; i < 8; ++i) v[i] = (short)e[i];
  pack[tid] = v;
}

// One block = 32 batch rows, 8 waves; wave w owns output cols [w*32, w*32+32).
// h (bf16, XOR-swizzled) double-buffered in LDS. 17 MFMAs per wave per step.
__global__ __launch_bounds__(512, 1) void enc_kernel(
    const float* __restrict__ path, const bf16x8* __restrict__ pack,
    float* __restrict__ out) {
  __shared__ __align__(16) char lds[32768];
  const int tid = threadIdx.x;
  const int lane = tid & 63;
  const int w = tid >> 6;        // wave id 0..7 = col tile
  const int col = lane & 31;     // A-row / B-col / C-col
  const int g = lane >> 5;       // k-group
  const int b0 = blockIdx.x * 32;

  // zero h buffer 0 (h0 = 0): 512 threads x 32B = 16 KB
  {
    int4 z = make_int4(0, 0, 0, 0);
    *reinterpret_cast<int4*>(lds + tid * 32) = z;
    *reinterpret_cast<int4*>(lds + tid * 32 + 16) = z;
  }
  __syncthreads();

  const float4* prow =
      reinterpret_cast<const float4*>(path + (size_t)(b0 + col) * 128);

  int cur = 0;
  const int swz = col << 4;

  for (int p = 0; p < NPTS; ++p) {
    const bf16x8* Bp = pack + (size_t)((p * 8 + w) * NKB) * 64 + lane;

    f32x16 acc0, acc1;
#pragma unroll
    for (int i = 0; i < 16; ++i) { acc0[i] = 0.0f; acc1[i] = 0.0f; }

    // x/bias A-fragment: lanes with g==0 hold [x0,x1,x2,x3,1.0,0,0,0]
    float4 px = prow[p];
    bf16x8 ax;
#pragma unroll
    for (int i = 0; i < 8; ++i) ax[i] = 0;
    if (g == 0) {
      ax[0] = (short)f2bf(px.x);
      ax[1] = (short)f2bf(px.y);
      ax[2] = (short)f2bf(px.z);
      ax[3] = (short)f2bf(px.w);
      ax[4] = (short)0x3F80;  // bf16 1.0 pairs with bias row in B
    }

    const char* hb = lds + cur * 16384;
#pragma unroll
    for (int kb = 0; kb < 16; ++kb) {
      bf16x8 a = *reinterpret_cast<const bf16x8*>(
          hb + col * 512 + ((kb * 32 + g * 16) ^ swz));
      bf16x8 bb = Bp[kb * 64];
      if (kb & 1)
        acc1 = __builtin_amdgcn_mfma_f32_32x32x16_bf16(a, bb, acc1, 0, 0, 0);
      else
        acc0 = __builtin_amdgcn_mfma_f32_32x32x16_bf16(a, bb, acc0, 0, 0, 0);
    }
    acc0 = __builtin_amdgcn_mfma_f32_32x32x16_bf16(ax, Bp[16 * 64], acc0, 0, 0, 0);

    // epilogue: relu, store fp32 to out, store bf16 h_next to other LDS buf
    char* hn = lds + (cur ^ 1) * 16384;
    float* outp = out + (size_t)b0 * OUTSTRIDE + p * 256 + w * 32 + col;
#pragma unroll
    for (int r = 0; r < 16; ++r) {
      int rr = (r & 3) + 8 * (r >> 2) + 4 * g;  // C/D row (verified layout)
      float v = fmaxf(acc0[r] + acc1[r], 0.0f);
      outp[(size_t)rr * OUTSTRIDE] = v;
      *reinterpret_cast<unsigned short*>(
          hn + rr * 512 + (((w * 32 + col) * 2) ^ (rr << 4))) = f2bf(v);
    }
    __syncthreads();
    cur ^= 1;
  }
}

extern "C" void kernel_launch(void* const* d_in, const int* in_sizes, int n_in,
                              void* d_out, int out_size, void* d_ws,
                              size_t ws_size, hipStream_t stream) {
  const float* path = (const float*)d_in[0];  // [8192][128]
  const float* W = (const float*)d_in[1];     // [32][256][260]
  const float* bias = (const float*)d_in[2];  // [32][256]
  float* out = (float*)d_out;                 // [8192][8192]
  bf16x8* pack = (bf16x8*)d_ws;               // 32*8*17*64 frags = 4.25 MB

  prep_kernel<<<1088, 256, 0, stream>>>(W, bias, pack);
  enc_kernel<<<256, 512, 0, stream>>>(path, pack, out);
}

// Round 2
// 93.536 us; speedup vs baseline: 1.0769x; 1.0769x over previous
//
#include <hip/hip_runtime.h>

typedef __attribute__((ext_vector_type(8))) short bf16x8;
typedef __attribute__((ext_vector_type(16))) float f32x16;

#define NPTS 32
#define HID 256
#define FANIN 260
#define NKB 17   // 16 h K-blocks (K=16 each) + 1 x/bias block
#define OUTSTRIDE 8192  // NPTS*HID

__device__ __forceinline__ unsigned short f2bf(float f) {
  unsigned u = __builtin_bit_cast(unsigned, f);
  u += 0x7fffu + ((u >> 16) & 1u);   // round-to-nearest-even
  return (unsigned short)(u >> 16);
}

// Pack W (fp32 [32][256][260]) + b (fp32 [32][256]) into per-lane MFMA
// B-fragments, bf16. pack[((p*8 + ct)*17 + kb)*64 + lane] = 8 bf16.
// kb<16: B[k = kb*16 + (lane>>5)*8 + i][n = ct*32 + (lane&31)] = W[p][n][k]
// kb==16 (x/bias): k=0..3 -> W[p][n][256+k], k=4 -> b[p][n], rest 0.
__global__ __launch_bounds__(256) void prep_kernel(
    const float* __restrict__ W, const float* __restrict__ bias,
    bf16x8* __restrict__ pack) {
  int tid = blockIdx.x * 256 + threadIdx.x;
  int lane = tid & 63;
  int kb = (tid >> 6) % NKB;
  int rest = (tid >> 6) / NKB;
  int ct = rest & 7;
  int p = rest >> 3;
  if (p >= NPTS) return;
  int n = ct * 32 + (lane & 31);
  int g = lane >> 5;
  const float* wrow = W + (size_t)(p * HID + n) * FANIN;
  unsigned short e[8];
  if (kb < 16) {
    int k0 = kb * 16 + g * 8;
#pragma unroll
    for (int i = 0; i < 8; ++i) e[i] = f2bf(wrow[k0 + i]);
  } else {
#pragma unroll
    for (int i = 0; i < 8; ++i) e[i] = 0;
    if (g == 0) {
      e[0] = f2bf(wrow[256]);
      e[1] = f2bf(wrow[257]);
      e[2] = f2bf(wrow[258]);
      e[3] = f2bf(wrow[259]);
      e[4] = f2bf(bias[p * HID + n]);
    }
  }
  bf16x8 v;
#pragma unroll
  for (int i = 0; i < 8; ++i) v[i] = (short)e[i];
  pack[tid] = v;
}

// One block = 32 batch rows, 8 waves; wave w owns output cols [w*32, w*32+32).
// h (bf16, XOR-swizzled) double-buffered in LDS. Per step: 17 MFMAs/wave.
// Key: raw s_barrier + lgkmcnt(0)-only (NO vmcnt drain) so the 16 output
// stores per lane per step stream to HBM across barriers; W-fragments for
// step p+1 are register-double-buffered and issued BEFORE step p's stores
// (vmcnt FIFO: a load waits for all earlier stores to retire).
__global__ __launch_bounds__(512, 2) void enc_kernel(
    const float* __restrict__ path, const bf16x8* __restrict__ pack,
    float* __restrict__ out) {
  __shared__ __align__(16) char lds[32768];
  const int tid = threadIdx.x;
  const int lane = tid & 63;
  const int w = tid >> 6;        // wave id 0..7 = col tile
  const int col = lane & 31;     // A-row / B-col / C-col
  const int g = lane >> 5;       // k-group
  const int b0 = blockIdx.x * 32;

  // zero h buffer 0 (h0 = 0)
  {
    int4 z = make_int4(0, 0, 0, 0);
    *reinterpret_cast<int4*>(lds + tid * 32) = z;
    *reinterpret_cast<int4*>(lds + tid * 32 + 16) = z;
  }

  const float4* prow =
      reinterpret_cast<const float4*>(path + (size_t)(b0 + col) * 128);
  float* outbase = out + (size_t)b0 * OUTSTRIDE;
  const int swz = col << 4;
  int cur = 0;

  bf16x8 BA[NKB], BB[NKB];
  float4 pxA, pxB;
  {
    const bf16x8* Bp0 = pack + (size_t)w * NKB * 64 + lane;
#pragma unroll
    for (int kb = 0; kb < NKB; ++kb) BA[kb] = Bp0[kb * 64];
    pxA = prow[0];
  }
  __syncthreads();  // once; drains the preloads too, fine

#define STEP(P, BC, BN, PX, PXN, PNEXT)                                       \
  {                                                                           \
    const int p_ = (P);                                                       \
    const bf16x8* Bnp =                                                       \
        pack + ((size_t)((PNEXT) * 8 + w) * NKB) * 64 + lane;                 \
    f32x16 acc0, acc1;                                                        \
    _Pragma("unroll") for (int i = 0; i < 16; ++i) {                          \
      acc0[i] = 0.0f;                                                         \
      acc1[i] = 0.0f;                                                         \
    }                                                                         \
    bf16x8 ax;                                                                \
    _Pragma("unroll") for (int i = 0; i < 8; ++i) ax[i] = 0;                  \
    if (g == 0) {                                                             \
      ax[0] = (short)f2bf((PX).x);                                            \
      ax[1] = (short)f2bf((PX).y);                                            \
      ax[2] = (short)f2bf((PX).z);                                            \
      ax[3] = (short)f2bf((PX).w);                                            \
      ax[4] = (short)0x3F80; /* 1.0 pairs with bias row in B */               \
    }                                                                         \
    const char* hb = lds + cur * 16384;                                       \
    _Pragma("unroll") for (int kb = 0; kb < 16; ++kb) {                       \
      bf16x8 a = *reinterpret_cast<const bf16x8*>(                            \
          hb + col * 512 + ((kb * 32 + g * 16) ^ swz));                       \
      if (kb & 1)                                                             \
        acc1 = __builtin_amdgcn_mfma_f32_32x32x16_bf16(a, (BC)[kb], acc1,     \
                                                       0, 0, 0);              \
      else                                                                    \
        acc0 = __builtin_amdgcn_mfma_f32_32x32x16_bf16(a, (BC)[kb], acc0,     \
                                                       0, 0, 0);              \
      (BN)[kb] = Bnp[kb * 64]; /* prefetch: issued BEFORE this step's stores */\
    }                                                                         \
    acc0 = __builtin_amdgcn_mfma_f32_32x32x16_bf16(ax, (BC)[16], acc0,        \
                                                   0, 0, 0);                  \
    (BN)[16] = Bnp[16 * 64];                                                  \
    (PXN) = prow[(PNEXT)];                                                    \
    char* hn = lds + (cur ^ 1) * 16384;                                       \
    float* outp = outbase + p_ * 256 + w * 32 + col;                          \
    _Pragma("unroll") for (int r = 0; r < 16; ++r) {                          \
      int rr = (r & 3) + 8 * (r >> 2) + 4 * g; /* C/D row (verified) */       \
      float v = fmaxf(acc0[r] + acc1[r], 0.0f);                               \
      __builtin_nontemporal_store(v, outp + (size_t)rr * OUTSTRIDE);          \
      *reinterpret_cast<unsigned short*>(                                     \
          hn + rr * 512 + (((w * 32 + col) * 2) ^ (rr << 4))) = f2bf(v);      \
    }                                                                         \
    asm volatile("s_waitcnt lgkmcnt(0)" ::: "memory");                        \
    __builtin_amdgcn_s_barrier();                                             \
    cur ^= 1;                                                                 \
  }

  for (int p = 0; p < NPTS; p += 2) {
    const int pn2 = (p + 2 < NPTS) ? (p + 2) : 0;  // clamp: harmless re-read
    STEP(p, BA, BB, pxA, pxB, (p + 1));
    STEP((p + 1), BB, BA, pxB, pxA, pn2);
  }
#undef STEP
}

extern "C" void kernel_launch(void* const* d_in, const int* in_sizes, int n_in,
                              void* d_out, int out_size, void* d_ws,
                              size_t ws_size, hipStream_t stream) {
  const float* path = (const float*)d_in[0];  // [8192][128]
  const float* W = (const float*)d_in[1];     // [32][256][260]
  const float* bias = (const float*)d_in[2];  // [32][256]
  float* out = (float*)d_out;                 // [8192][8192]
  bf16x8* pack = (bf16x8*)d_ws;               // 32*8*17*64 frags = 4.25 MB

  prep_kernel<<<1088, 256, 0, stream>>>(W, bias, pack);
  enc_kernel<<<256, 512, 0, stream>>>(path, pack, out);
}